// Round 14
// baseline (259.568 us; speedup 1.0000x reference)
//
#include <hip/hip_runtime.h>
#include <stdint.h>

#define TPB 256
#define BM 16
#define CTXD 256
#define HID 128
#define TSTEPS 48
#define DTC (1.0f/30.0f)

typedef short short8 __attribute__((ext_vector_type(8)));
typedef float f32x4 __attribute__((ext_vector_type(4)));
typedef float f32x2 __attribute__((ext_vector_type(2)));

// ---------------- LDS layout (bytes), per block — 41.5 KB -> 2 blocks/CU ----------------
// W_N / h tiles: stride 256B, XOR swizzle byte ^= (row&15)<<4 -> conflict-free b128.
#define OFF_WN   0                // W_hh N-gate bf16 [128][128] = 32768
#define OFF_H    32768            // loop: 2 x h bf16 [16][128] (4096 each); phase A: ctx bf16 [16][256] (8192)
#define HBUFSZ   4096
#define CSTRIDE  512
#define OFF_PART 40960            // delta partials f32 [16 rows][4 jt][2] = 512
#define LDS_BYTES 41472

__device__ __forceinline__ uint32_t cvtpk_bf16(float lo, float hi) {
    uint32_t r;
    asm("v_cvt_pk_bf16_f32 %0, %1, %2" : "=v"(r) : "v"(lo), "v"(hi));
    return r;
}
__device__ __forceinline__ uint32_t pkh2(float a, float b) {
    union { _Float16 h[2]; uint32_t u; } v;
    v.h[0] = (_Float16)a; v.h[1] = (_Float16)b; return v.u;
}
__device__ __forceinline__ float h2lo(uint32_t u) {
    union { uint32_t u; _Float16 h[2]; } v; v.u = u; return (float)v.h[0];
}
__device__ __forceinline__ float h2hi(uint32_t u) {
    union { uint32_t u; _Float16 h[2]; } v; v.u = u; return (float)v.h[1];
}
__device__ __forceinline__ float fsigm(float x) {
    return __builtin_amdgcn_rcpf(1.0f + __expf(-x));
}
__device__ __forceinline__ float ftanhf(float x) {
    return fmaf(-2.0f, __builtin_amdgcn_rcpf(1.0f + __expf(2.0f * x)), 1.0f);
}
__device__ __forceinline__ short8 ldA8(const float* src) {
    f32x2 v0 = *(const f32x2*)(src + 0);
    f32x2 v1 = *(const f32x2*)(src + 2);
    f32x2 v2 = *(const f32x2*)(src + 4);
    f32x2 v3 = *(const f32x2*)(src + 6);
    union { short8 s; uint32_t u[4]; } r;
    r.u[0] = cvtpk_bf16(v0.x, v0.y);
    r.u[1] = cvtpk_bf16(v1.x, v1.y);
    r.u[2] = cvtpk_bf16(v2.x, v2.y);
    r.u[3] = cvtpk_bf16(v3.x, v3.y);
    return r.s;
}

// OCCUPANCY MODEL (R1-R13): launch_bounds 2nd arg = min waves/EU sets the
// unified VGPR+AGPR budget = 512/arg. Occupancy moves in whole BLOCKS:
// an 8-wave block gives only 8 or 16 waves/CU, and 16 needs <=128 regs
// (spills). R14: two INDEPENDENT 4-wave blocks at budget 256 — same 8
// waves/CU, but block B issues while block A waits at its barrier.
__global__ __launch_bounds__(TPB, 2)
void dd_kernel(const float* __restrict__ ctx, const float* __restrict__ lv,
               const float* __restrict__ Winit, const float* __restrict__ binit,
               const float* __restrict__ Wih, const float* __restrict__ bih,
               const float* __restrict__ Whh, const float* __restrict__ bhh,
               const float* __restrict__ W1, const float* __restrict__ b1,
               const float* __restrict__ W2, const float* __restrict__ b2,
               float* __restrict__ out)
{
    extern __shared__ char smem[];
    const int tid  = threadIdx.x;
    const int w    = tid >> 6;          // wave 0..3; GRU units 32w..32w+31; MLP tile jt = w
    const int lane = tid & 63;
    const int g    = (lane >> 4) & 3;
    const int l15  = lane & 15;
    const int row0 = blockIdx.x * BM;

    // ---------------- stage LDS: W_N + ctx (swizzled) ----------------
    for (int p = tid; p < 128 * 64; p += TPB) {           // W_hh N-gate rows 256..383
        int u = p >> 6, kp = p & 63;
        f32x2 v = *(const f32x2*)(Whh + (size_t)(256 + u) * HID + 2 * kp);
        *(uint32_t*)(smem + OFF_WN + u * 256 + ((4 * kp) ^ ((u & 15) << 4))) = cvtpk_bf16(v.x, v.y);
    }
    for (int p = tid; p < 16 * 128; p += TPB) {           // ctx (phase A)
        int r = p >> 7, kp = p & 127;
        f32x2 v = *(const f32x2*)(ctx + (size_t)(row0 + r) * CTXD + 2 * kp);
        *(uint32_t*)(smem + OFF_H + r * CSTRIDE + ((4 * kp) ^ ((r & 15) << 4))) = cvtpk_bf16(v.x, v.y);
    }

    const int u16a = 32 * w + l15;       // unit-tile 0 row
    const int u16b = u16a + 16;          // unit-tile 1 row
    const float b2c0 = b2[0], b2c1 = b2[1];
    float dx, dy, pos0v, pos1v;
    {
        f32x2 v = *(const f32x2*)(lv + (size_t)(row0 + l15) * 2);
        dx = v.x * DTC; dy = v.y * DTC; pos0v = 0.f; pos1v = 0.f;
    }

    // ---------------- per-lane loop constants (registers; budget 256) ----------------
    float b1c[4], w2c0[4], w2c1[4];
    uint32_t wdrp[2][4], wdzp[2][4], wdnp[2][4];
    float bhnc[2][4];
#pragma unroll
    for (int r = 0; r < 4; ++r) {
        int um = 16 * w + 4 * g + r;
        b1c[r]  = b1[um];
        w2c0[r] = W2[um];
        w2c1[r] = W2[64 + um];
    }
#pragma unroll
    for (int i = 0; i < 2; ++i)
#pragma unroll
        for (int r = 0; r < 4; ++r) {
            int u = 32 * w + 16 * i + 4 * g + r;
            wdrp[i][r] = pkh2(Wih[(size_t)u * 258], Wih[(size_t)u * 258 + 1]);
            wdzp[i][r] = pkh2(Wih[(size_t)(128 + u) * 258], Wih[(size_t)(128 + u) * 258 + 1]);
            wdnp[i][r] = pkh2(Wih[(size_t)(256 + u) * 258], Wih[(size_t)(256 + u) * 258 + 1]);
            bhnc[i][r] = bhh[256 + u];
        }

    __syncthreads();

    // ---------------- Phase A: gi (2 unit-tiles) + h0 ----------------
    f32x4 zero4 = {0.f, 0.f, 0.f, 0.f};
    f32x4 accA[4][2];                   // {R,Z,N,H0} x unit-tile
#pragma unroll
    for (int jl = 0; jl < 4; ++jl) { accA[jl][0] = zero4; accA[jl][1] = zero4; }

    const int cswz = (16 * g) ^ (l15 << 4);
    for (int kk = 0; kk < 8; ++kk) {
        const int cx = cswz ^ (64 * kk);
        short8 bf  = *(const short8*)(smem + OFF_H + l15 * CSTRIDE + cx);
        short8 aR0 = ldA8(Wih + (size_t)u16a * 258 + 2 + 32 * kk + 8 * g);
        short8 aR1 = ldA8(Wih + (size_t)u16b * 258 + 2 + 32 * kk + 8 * g);
        short8 aZ0 = ldA8(Wih + (size_t)(128 + u16a) * 258 + 2 + 32 * kk + 8 * g);
        short8 aZ1 = ldA8(Wih + (size_t)(128 + u16b) * 258 + 2 + 32 * kk + 8 * g);
        short8 aN0 = ldA8(Wih + (size_t)(256 + u16a) * 258 + 2 + 32 * kk + 8 * g);
        short8 aN1 = ldA8(Wih + (size_t)(256 + u16b) * 258 + 2 + 32 * kk + 8 * g);
        short8 aH0 = ldA8(Winit + (size_t)u16a * 256 + 32 * kk + 8 * g);
        short8 aH1 = ldA8(Winit + (size_t)u16b * 256 + 32 * kk + 8 * g);
        accA[0][0] = __builtin_amdgcn_mfma_f32_16x16x32_bf16(aR0, bf, accA[0][0], 0, 0, 0);
        accA[0][1] = __builtin_amdgcn_mfma_f32_16x16x32_bf16(aR1, bf, accA[0][1], 0, 0, 0);
        accA[1][0] = __builtin_amdgcn_mfma_f32_16x16x32_bf16(aZ0, bf, accA[1][0], 0, 0, 0);
        accA[1][1] = __builtin_amdgcn_mfma_f32_16x16x32_bf16(aZ1, bf, accA[1][1], 0, 0, 0);
        accA[2][0] = __builtin_amdgcn_mfma_f32_16x16x32_bf16(aN0, bf, accA[2][0], 0, 0, 0);
        accA[2][1] = __builtin_amdgcn_mfma_f32_16x16x32_bf16(aN1, bf, accA[2][1], 0, 0, 0);
        accA[3][0] = __builtin_amdgcn_mfma_f32_16x16x32_bf16(aH0, bf, accA[3][0], 0, 0, 0);
        accA[3][1] = __builtin_amdgcn_mfma_f32_16x16x32_bf16(aH1, bf, accA[3][1], 0, 0, 0);
    }

    // gi pack (f16, registers) + h0 master copy f32
    uint32_t gipR[2][2], gipZ[2][2], gipN[2][2];
    float hm[2][4];
#pragma unroll
    for (int i = 0; i < 2; ++i) {
        float tb0[4], tb1[4], tb2[4], tb3[4];
#pragma unroll
        for (int r = 0; r < 4; ++r) {
            int u = 32 * w + 16 * i + 4 * g + r;
            tb0[r] = bih[u] + bhh[u];
            tb1[r] = bih[128 + u] + bhh[128 + u];
            tb2[r] = bih[256 + u];
            tb3[r] = binit[u];
        }
        gipR[i][0] = pkh2(accA[0][i][0] + tb0[0], accA[0][i][1] + tb0[1]);
        gipR[i][1] = pkh2(accA[0][i][2] + tb0[2], accA[0][i][3] + tb0[3]);
        gipZ[i][0] = pkh2(accA[1][i][0] + tb1[0], accA[1][i][1] + tb1[1]);
        gipZ[i][1] = pkh2(accA[1][i][2] + tb1[2], accA[1][i][3] + tb1[3]);
        gipN[i][0] = pkh2(accA[2][i][0] + tb2[0], accA[2][i][1] + tb2[1]);
        gipN[i][1] = pkh2(accA[2][i][2] + tb2[2], accA[2][i][3] + tb2[3]);
#pragma unroll
        for (int r = 0; r < 4; ++r)
            hm[i][r] = ftanhf(accA[3][i][r] + tb3[r]);
    }

    // register-resident weights (loaded AFTER phase A: no overlap with accA peak)
    short8 wfr[2][4], wfz[2][4], wf1[4];
#pragma unroll
    for (int kk = 0; kk < 4; ++kk) {
        wfr[0][kk] = ldA8(Whh + (size_t)u16a * HID + 32 * kk + 8 * g);
        wfr[1][kk] = ldA8(Whh + (size_t)u16b * HID + 32 * kk + 8 * g);
        wfz[0][kk] = ldA8(Whh + (size_t)(128 + u16a) * HID + 32 * kk + 8 * g);
        wfz[1][kk] = ldA8(Whh + (size_t)(128 + u16b) * HID + 32 * kk + 8 * g);
        wf1[kk]    = ldA8(W1 + (size_t)(16 * w + l15) * HID + 32 * kk + 8 * g);
    }

    __syncthreads();              // ctx reads done; h region reusable

#pragma unroll
    for (int i = 0; i < 2; ++i) { // h0 -> buf0
        uint2 pk;
        pk.x = cvtpk_bf16(hm[i][0], hm[i][1]);
        pk.y = cvtpk_bf16(hm[i][2], hm[i][3]);
        *(uint2*)(smem + OFF_H + l15 * 256 + ((64 * w + 32 * i + 8 * g) ^ (l15 << 4))) = pk;
    }
    __syncthreads();

    const int uNa = OFF_WN + u16a * 256;
    const int uNb = OFF_WN + u16b * 256;

    // ---------------- recurrence: 49 iterations (t==TSTEPS = MLP-only tail) ----------------
    for (int t = 0; t <= TSTEPS; ++t) {
        const int rbuf = OFF_H + (t & 1) * HBUFSZ;         // h_t
        const int wbuf = OFF_H + ((t + 1) & 1) * HBUFSZ;   // h_{t+1}
        f32x4 aR[2], aZ[2], aN[2];
        f32x4 a1 = zero4;
        if (t < TSTEPS) {
#pragma unroll
            for (int i = 0; i < 2; ++i) {
                aR[i][0] = h2lo(gipR[i][0]); aR[i][1] = h2hi(gipR[i][0]);
                aR[i][2] = h2lo(gipR[i][1]); aR[i][3] = h2hi(gipR[i][1]);
                aZ[i][0] = h2lo(gipZ[i][0]); aZ[i][1] = h2hi(gipZ[i][0]);
                aZ[i][2] = h2lo(gipZ[i][1]); aZ[i][3] = h2hi(gipZ[i][1]);
#pragma unroll
                for (int r = 0; r < 4; ++r) aN[i][r] = bhnc[i][r];
            }
#pragma unroll
            for (int kk = 0; kk < 4; ++kk) {
                const int cx = cswz ^ (64 * kk);
                short8 bf  = *(const short8*)(smem + rbuf + l15 * 256 + cx);
                short8 fN0 = *(const short8*)(smem + uNa + cx);
                short8 fN1 = *(const short8*)(smem + uNb + cx);
                aR[0] = __builtin_amdgcn_mfma_f32_16x16x32_bf16(wfr[0][kk], bf, aR[0], 0, 0, 0);
                aR[1] = __builtin_amdgcn_mfma_f32_16x16x32_bf16(wfr[1][kk], bf, aR[1], 0, 0, 0);
                aZ[0] = __builtin_amdgcn_mfma_f32_16x16x32_bf16(wfz[0][kk], bf, aZ[0], 0, 0, 0);
                aZ[1] = __builtin_amdgcn_mfma_f32_16x16x32_bf16(wfz[1][kk], bf, aZ[1], 0, 0, 0);
                aN[0] = __builtin_amdgcn_mfma_f32_16x16x32_bf16(fN0, bf, aN[0], 0, 0, 0);
                aN[1] = __builtin_amdgcn_mfma_f32_16x16x32_bf16(fN1, bf, aN[1], 0, 0, 0);
                a1    = __builtin_amdgcn_mfma_f32_16x16x32_bf16(wf1[kk], bf, a1, 0, 0, 0);
            }
        } else {                   // tail: MLP(h_48) only
#pragma unroll
            for (int kk = 0; kk < 4; ++kk) {
                const int cx = cswz ^ (64 * kk);
                short8 bf = *(const short8*)(smem + rbuf + l15 * 256 + cx);
                a1 = __builtin_amdgcn_mfma_f32_16x16x32_bf16(wf1[kk], bf, a1, 0, 0, 0);
            }
        }
        // MLP epilogue -> partial (jt = w)
        {
            float s0 = 0.f, s1 = 0.f;
#pragma unroll
            for (int r = 0; r < 4; ++r) {
                float hv = fmaxf(a1[r] + b1c[r], 0.f);
                s0 = fmaf(hv, w2c0[r], s0);
                s1 = fmaf(hv, w2c1[r], s1);
            }
            s0 += __shfl_xor(s0, 16, 64); s0 += __shfl_xor(s0, 32, 64);
            s1 += __shfl_xor(s1, 16, 64); s1 += __shfl_xor(s1, 32, 64);
            if (lane < 16) {
                f32x2 pw; pw.x = s0; pw.y = s1;
                *(f32x2*)(smem + OFF_PART + l15 * 32 + w * 8) = pw;
            }
        }
        __syncthreads();          // barrier B: partials visible
        if (t > 0) {
            f32x4 q0 = *(const f32x4*)(smem + OFF_PART + l15 * 32);
            f32x4 q1 = *(const f32x4*)(smem + OFF_PART + l15 * 32 + 16);
            float pdx = (q0[0] + q0[2]) + (q1[0] + q1[2]) + b2c0;
            float pdy = (q0[1] + q0[3]) + (q1[1] + q1[3]) + b2c1;
            dx = pdx; dy = pdy;
            pos0v += pdx; pos1v += pdy;
            if (w == 0 && lane < 16) {
                f32x2 o2; o2.x = pos0v; o2.y = pos1v;
                *(f32x2*)(out + (size_t)(row0 + l15) * (TSTEPS * 2) + 2 * (t - 1)) = o2;
            }
        }
        if (t < TSTEPS) {
            // gates: all tables register-resident; f16 halves inlined in fma
#pragma unroll
            for (int i = 0; i < 2; ++i) {
#pragma unroll
                for (int r = 0; r < 4; ++r) {
                    float rr  = fsigm(fmaf(dy, h2hi(wdrp[i][r]), fmaf(dx, h2lo(wdrp[i][r]), aR[i][r])));
                    float zz  = fsigm(fmaf(dy, h2hi(wdzp[i][r]), fmaf(dx, h2lo(wdzp[i][r]), aZ[i][r])));
                    float gnv = (r & 1) ? h2hi(gipN[i][r >> 1]) : h2lo(gipN[i][r >> 1]);
                    float inn = fmaf(dy, h2hi(wdnp[i][r]), fmaf(dx, h2lo(wdnp[i][r]), gnv));
                    float nn  = ftanhf(fmaf(rr, aN[i][r], inn));
                    hm[i][r]  = fmaf(zz, hm[i][r] - nn, nn);
                }
                uint2 pk;
                pk.x = cvtpk_bf16(hm[i][0], hm[i][1]);
                pk.y = cvtpk_bf16(hm[i][2], hm[i][3]);
                *(uint2*)(smem + wbuf + l15 * 256 + ((64 * w + 32 * i + 8 * g) ^ (l15 << 4))) = pk;
            }
        }
        __syncthreads();          // barrier A: h_{t+1} visible
    }
}

extern "C" void kernel_launch(void* const* d_in, const int* in_sizes, int n_in,
                              void* d_out, int out_size, void* d_ws, size_t ws_size,
                              hipStream_t stream) {
    (void)in_sizes; (void)n_in; (void)d_ws; (void)ws_size; (void)out_size;
    const float* ctx   = (const float*)d_in[0];
    const float* lv    = (const float*)d_in[1];
    const float* Winit = (const float*)d_in[2];
    const float* binit = (const float*)d_in[3];
    const float* Wih   = (const float*)d_in[4];
    const float* bih   = (const float*)d_in[5];
    const float* Whh   = (const float*)d_in[6];
    const float* bhh   = (const float*)d_in[7];
    const float* W1    = (const float*)d_in[8];
    const float* b1    = (const float*)d_in[9];
    const float* W2    = (const float*)d_in[10];
    const float* b2    = (const float*)d_in[11];
    float* out = (float*)d_out;

    hipFuncSetAttribute(reinterpret_cast<const void*>(dd_kernel),
                        hipFuncAttributeMaxDynamicSharedMemorySize, LDS_BYTES);
    dd_kernel<<<16384 / BM, TPB, LDS_BYTES, stream>>>(
        ctx, lv, Winit, binit, Wih, bih, Whh, bhh, W1, b1, W2, b2, out);
}